// Round 1
// baseline (7244.503 us; speedup 1.0000x reference)
//
#include <hip/hip_runtime.h>
#include <hip/hip_bf16.h>
#include <math.h>

#define SEQ 512
#define NB  128
#define NIN 512
#define NH  1024

typedef __attribute__((ext_vector_type(8))) short short8;
typedef __attribute__((ext_vector_type(4))) float f32x4;

__device__ __forceinline__ unsigned short bf16b(float f) {
  __hip_bfloat16 h = __float2bfloat16(f);
  return *reinterpret_cast<unsigned short*>(&h);
}

// ---- Wh fp32 [NH][NH] -> WhT bf16 [c][k] ----
__global__ void k_cvt_whT(const float* __restrict__ wh, unsigned short* __restrict__ whT) {
  int idx = blockIdx.x * 256 + threadIdx.x;   // over NH*NH
  int k = idx >> 10, c = idx & (NH - 1);
  whT[(size_t)c * NH + k] = bf16b(wh[idx]);
}

// ---- Wx fp32 [NIN][NH] -> WxT bf16 [c][k] ----
__global__ void k_cvt_wxT(const float* __restrict__ wx, unsigned short* __restrict__ wxT) {
  int idx = blockIdx.x * 256 + threadIdx.x;   // over NIN*NH
  int k = idx >> 10, c = idx & (NH - 1);
  wxT[(size_t)c * NIN + k] = bf16b(wx[idx]);
}

// ---- initial_state fp32 [NB][NH] -> fragment-packed bf16 state buffer ----
// packing: element (row,k) -> chunk (mg=row>>4, kc=k>>5), lane=(row&15)|(((k&31)>>3)<<4), elem=k&7
__global__ void k_init_state(const float* __restrict__ s0, unsigned short* __restrict__ sbuf) {
  int idx = blockIdx.x * 256 + threadIdx.x;   // over NB*NH
  int row = idx >> 10, k = idx & (NH - 1);
  int mg = row >> 4, kc = k >> 5, g = (k & 31) >> 3, i = k & 7;
  int ln = (row & 15) | (g << 4);
  sbuf[((size_t)(mg * 32 + kc) * 64 + ln) * 8 + i] = bf16b(s0[idx]);
}

// ---- Phase 1: xw = input @ Wx + bias  -> written fp32 into d_out states region ----
__launch_bounds__(256)
__global__ void k_xw_gemm(const float* __restrict__ x, const unsigned short* __restrict__ wxT,
                          const float* __restrict__ bias, float* __restrict__ out) {
  __shared__ unsigned short a_lds[128 * 40];  // [row][k], stride 40 ushorts (80B, 16B-aligned rows)
  __shared__ unsigned short b_lds[128 * 40];  // [col][k]
  const int bx = blockIdx.x;
  const int n0 = (bx & 7) * 128;
  const int m0 = (bx >> 3) * 128;
  const int tid = threadIdx.x, lane = tid & 63, w = tid >> 6;
  const int wr = w >> 1, wc = w & 1;
  f32x4 acc[4][4] = {};
  for (int k0 = 0; k0 < NIN; k0 += 32) {
    // stage A (fp32 -> bf16): 128 rows x 32 k
    {
      int j = tid & 7, rr = tid >> 3;  // 8 float4 per row, 32 rows per pass
      #pragma unroll
      for (int p = 0; p < 4; ++p) {
        int row = p * 32 + rr;
        const float4 v = *reinterpret_cast<const float4*>(&x[(size_t)(m0 + row) * NIN + k0 + 4 * j]);
        unsigned int lo = bf16b(v.x) | ((unsigned int)bf16b(v.y) << 16);
        unsigned int hi = bf16b(v.z) | ((unsigned int)bf16b(v.w) << 16);
        *reinterpret_cast<uint2*>(&a_lds[row * 40 + 4 * j]) = make_uint2(lo, hi);
      }
    }
    // stage B (bf16 WxT [col][k]): 128 cols x 32 k
    {
      #pragma unroll
      for (int p = 0; p < 2; ++p) {
        int tt = p * 256 + tid;
        int col = tt >> 2, ko = (tt & 3) * 8;
        const uint4 v = *reinterpret_cast<const uint4*>(&wxT[(size_t)(n0 + col) * NIN + k0 + ko]);
        *reinterpret_cast<uint4*>(&b_lds[col * 40 + ko]) = v;
      }
    }
    __syncthreads();
    short8 af[4], bf[4];
    #pragma unroll
    for (int bi = 0; bi < 4; ++bi)
      af[bi] = *reinterpret_cast<const short8*>(&a_lds[(wr * 64 + bi * 16 + (lane & 15)) * 40 + (lane >> 4) * 8]);
    #pragma unroll
    for (int bj = 0; bj < 4; ++bj)
      bf[bj] = *reinterpret_cast<const short8*>(&b_lds[(wc * 64 + bj * 16 + (lane & 15)) * 40 + (lane >> 4) * 8]);
    #pragma unroll
    for (int bi = 0; bi < 4; ++bi) {
      #pragma unroll
      for (int bj = 0; bj < 4; ++bj)
        acc[bi][bj] = __builtin_amdgcn_mfma_f32_16x16x32_bf16(af[bi], bf[bj], acc[bi][bj], 0, 0, 0);
    }
    __syncthreads();
  }
  #pragma unroll
  for (int bi = 0; bi < 4; ++bi) {
    #pragma unroll
    for (int bj = 0; bj < 4; ++bj) {
      int col = n0 + wc * 64 + bj * 16 + (lane & 15);
      float bv = bias[col];
      #pragma unroll
      for (int r = 0; r < 4; ++r) {
        int row = m0 + wr * 64 + bi * 16 + (lane >> 4) * 4 + r;
        out[(size_t)row * NH + col] = acc[bi][bj][r] + bv;
      }
    }
  }
}

// ---- Phase 2: persistent recurrent scan ----
// grid = 64 blocks: bg = bx>>5 (batch group of 64 rows), cg = bx&31 (32 cols each).
// Each block: Wh slice fragment-packed in LDS (stationary), per step:
//   acc = state(bf16 frag-packed global) @ Wh_slice ; out = tanh(acc + xw) ;
//   write fp32 states to d_out, bf16 frag-packed next-state; 32-block group barrier.
__launch_bounds__(256)
__global__ void k_scan(const unsigned short* __restrict__ whT,
                       float* __restrict__ out,
                       unsigned short* __restrict__ sb0,
                       unsigned short* __restrict__ sb1,
                       unsigned int* __restrict__ cnt) {
  __shared__ unsigned short b_lds[32 * 2 * 64 * 8];  // [kc][half][lane][8] = 64KB
  const int bx = blockIdx.x;
  const int bg = bx >> 5;   // 0..1
  const int cg = bx & 31;   // 0..31
  const int tid = threadIdx.x, lane = tid & 63, w = tid >> 6;  // w = m-group within block
  // stage WhT cols [cg*32, cg*32+32) fragment-packed
  {
    int c = tid >> 3;
    for (int it = 0; it < 32; ++it) {
      int kq = (tid & 7) + 8 * it;
      int k = kq * 4;
      uint2 v = *reinterpret_cast<const uint2*>(&whT[(size_t)(cg * 32 + c) * NH + k]);
      int kc = k >> 5, g = (k & 31) >> 3, i0 = k & 7, half = c >> 4;
      int ln = (c & 15) | (g << 4);
      *reinterpret_cast<uint2*>(&b_lds[((kc * 2 + half) * 64 + ln) * 8 + i0]) = v;
    }
  }
  __syncthreads();
  const int mg = bg * 4 + w;           // absolute m-group 0..7
  const int r0 = (lane >> 4) * 4;
  const int c0 = lane & 15;
  unsigned int target = 0;
  for (int t = 0; t < SEQ; ++t) {
    const unsigned short* cur = (t & 1) ? sb1 : sb0;
    unsigned short* nxt = (t & 1) ? sb0 : sb1;
    // prefetch xw (phase-1 data; we overwrite these addresses later this step)
    float xw[2][4];
    #pragma unroll
    for (int bj = 0; bj < 2; ++bj) {
      #pragma unroll
      for (int r = 0; r < 4; ++r)
        xw[bj][r] = out[(size_t)(t * NB + bg * 64 + w * 16 + r0 + r) * NH + cg * 32 + bj * 16 + c0];
    }
    f32x4 acc0 = {0.f, 0.f, 0.f, 0.f}, acc1 = {0.f, 0.f, 0.f, 0.f};
    const unsigned short* abase = cur + (size_t)(mg * 32) * 512 + lane * 8;
    #pragma unroll 8
    for (int kc = 0; kc < 32; ++kc) {
      short8 a  = *reinterpret_cast<const short8*>(abase + kc * 512);
      short8 b0 = *reinterpret_cast<const short8*>(&b_lds[((kc * 2 + 0) * 64 + lane) * 8]);
      short8 b1 = *reinterpret_cast<const short8*>(&b_lds[((kc * 2 + 1) * 64 + lane) * 8]);
      acc0 = __builtin_amdgcn_mfma_f32_16x16x32_bf16(a, b0, acc0, 0, 0, 0);
      acc1 = __builtin_amdgcn_mfma_f32_16x16x32_bf16(a, b1, acc1, 0, 0, 0);
    }
    #pragma unroll
    for (int bj = 0; bj < 2; ++bj) {
      const f32x4 accv = bj ? acc1 : acc0;
      #pragma unroll
      for (int r = 0; r < 4; ++r) {
        float v = tanhf(accv[r] + xw[bj][r]);
        int row = bg * 64 + w * 16 + r0 + r;
        int col = cg * 32 + bj * 16 + c0;
        out[(size_t)(t * NB + row) * NH + col] = v;
        int kk = bj * 16 + c0;
        int g = kk >> 3, i = kk & 7;
        int ln = (r0 + r) | (g << 4);
        nxt[((size_t)(mg * 32 + cg) * 64 + ln) * 8 + i] = bf16b(v);
      }
    }
    // 32-block group barrier (device-scope release/acquire)
    __threadfence();
    __syncthreads();
    target += 32;
    if (tid == 0) {
      __hip_atomic_fetch_add(&cnt[bg * 32], 1u, __ATOMIC_RELEASE, __HIP_MEMORY_SCOPE_AGENT);
      while (__hip_atomic_load(&cnt[bg * 32], __ATOMIC_ACQUIRE, __HIP_MEMORY_SCOPE_AGENT) < target) {
        __builtin_amdgcn_s_sleep(1);
      }
    }
    __syncthreads();
  }
}

extern "C" void kernel_launch(void* const* d_in, const int* in_sizes, int n_in,
                              void* d_out, int out_size, void* d_ws, size_t ws_size,
                              hipStream_t stream) {
  const float* x    = (const float*)d_in[0];
  const float* s0   = (const float*)d_in[1];
  const float* wx   = (const float*)d_in[2];
  const float* wh   = (const float*)d_in[3];
  const float* bias = (const float*)d_in[4];
  float* out = (float*)d_out;

  char* ws = (char*)d_ws;
  unsigned short* whT = (unsigned short*)(ws);                                  // 2 MB
  unsigned short* wxT = (unsigned short*)(ws + (2u << 20));                     // 1 MB
  unsigned short* sb0 = (unsigned short*)(ws + (3u << 20));                     // 256 KB
  unsigned short* sb1 = (unsigned short*)(ws + (3u << 20) + (256u << 10));      // 256 KB
  unsigned int*   cnt = (unsigned int*)(ws + (3u << 20) + (512u << 10));        // 256 B

  hipMemsetAsync(cnt, 0, 256, stream);
  k_cvt_whT<<<NH * NH / 256, 256, 0, stream>>>(wh, whT);
  k_cvt_wxT<<<NIN * NH / 256, 256, 0, stream>>>(wx, wxT);
  k_init_state<<<NB * NH / 256, 256, 0, stream>>>(s0, sb0);
  k_xw_gemm<<<(SEQ * NB / 128) * (NH / 128), 256, 0, stream>>>(x, wxT, bias, out);
  k_scan<<<64, 256, 0, stream>>>(whT, out, sb0, sb1, cnt);
  hipMemcpyAsync(out + (size_t)SEQ * NB * NH, out + (size_t)(SEQ - 1) * NB * NH,
                 (size_t)NB * NH * sizeof(float), hipMemcpyDeviceToDevice, stream);
}

// Round 2
// 2615.405 us; speedup vs baseline: 2.7699x; 2.7699x over previous
//
#include <hip/hip_runtime.h>
#include <hip/hip_bf16.h>
#include <math.h>

#define SEQ 512
#define NB  128
#define NIN 512
#define NH  1024

typedef __attribute__((ext_vector_type(8))) short short8;
typedef __attribute__((ext_vector_type(4))) float f32x4;
typedef unsigned int uint32;

__device__ __forceinline__ unsigned short bf16b(float f) {
  __hip_bfloat16 h = __float2bfloat16(f);
  return *reinterpret_cast<unsigned short*>(&h);
}

// ---- Wh fp32 [NH][NH] -> WhT bf16 [c][k] ----
__global__ void k_cvt_whT(const float* __restrict__ wh, unsigned short* __restrict__ whT) {
  int idx = blockIdx.x * 256 + threadIdx.x;   // over NH*NH
  int k = idx >> 10, c = idx & (NH - 1);
  whT[(size_t)c * NH + k] = bf16b(wh[idx]);
}

// ---- Wx fp32 [NIN][NH] -> WxT bf16 [c][k] ----
__global__ void k_cvt_wxT(const float* __restrict__ wx, unsigned short* __restrict__ wxT) {
  int idx = blockIdx.x * 256 + threadIdx.x;   // over NIN*NH
  int k = idx >> 10, c = idx & (NH - 1);
  wxT[(size_t)c * NIN + k] = bf16b(wx[idx]);
}

// ---- initial_state fp32 [NB][NH] -> state buffer, layout v2 ----
// chunk c = (mg=row>>4)*32 + (kc=k>>5); 256 dwords per chunk.
// within chunk: fragment lane ln=(row&15)|(((k&31)>>3)<<4); ushort idx i=(k&31)&7;
// dword j=i>>1, parity=i&1; dword position = j*64 + ln (lane-contiguous per j).
__global__ void k_init_state(const float* __restrict__ s0, unsigned short* __restrict__ sbuf) {
  int idx = blockIdx.x * 256 + threadIdx.x;   // over NB*NH
  int row = idx >> 10, k = idx & (NH - 1);
  int mg = row >> 4, kc = k >> 5;
  int kl = k & 31, g = kl >> 3, i = kl & 7;
  int ln = (row & 15) | (g << 4);
  int j = i >> 1, par = i & 1;
  sbuf[((size_t)(mg * 32 + kc) * 256 + j * 64 + ln) * 2 + par] = bf16b(s0[idx]);
}

// ---- Phase 1: xw = input @ Wx + bias  -> written fp32 into d_out states region ----
__launch_bounds__(256)
__global__ void k_xw_gemm(const float* __restrict__ x, const unsigned short* __restrict__ wxT,
                          const float* __restrict__ bias, float* __restrict__ out) {
  __shared__ unsigned short a_lds[128 * 40];
  __shared__ unsigned short b_lds[128 * 40];
  const int bx = blockIdx.x;
  const int n0 = (bx & 7) * 128;
  const int m0 = (bx >> 3) * 128;
  const int tid = threadIdx.x, lane = tid & 63, w = tid >> 6;
  const int wr = w >> 1, wc = w & 1;
  f32x4 acc[4][4] = {};
  for (int k0 = 0; k0 < NIN; k0 += 32) {
    {
      int j = tid & 7, rr = tid >> 3;
      #pragma unroll
      for (int p = 0; p < 4; ++p) {
        int row = p * 32 + rr;
        const float4 v = *reinterpret_cast<const float4*>(&x[(size_t)(m0 + row) * NIN + k0 + 4 * j]);
        unsigned int lo = bf16b(v.x) | ((unsigned int)bf16b(v.y) << 16);
        unsigned int hi = bf16b(v.z) | ((unsigned int)bf16b(v.w) << 16);
        *reinterpret_cast<uint2*>(&a_lds[row * 40 + 4 * j]) = make_uint2(lo, hi);
      }
    }
    {
      #pragma unroll
      for (int p = 0; p < 2; ++p) {
        int tt = p * 256 + tid;
        int col = tt >> 2, ko = (tt & 3) * 8;
        const uint4 v = *reinterpret_cast<const uint4*>(&wxT[(size_t)(n0 + col) * NIN + k0 + ko]);
        *reinterpret_cast<uint4*>(&b_lds[col * 40 + ko]) = v;
      }
    }
    __syncthreads();
    short8 af[4], bf[4];
    #pragma unroll
    for (int bi = 0; bi < 4; ++bi)
      af[bi] = *reinterpret_cast<const short8*>(&a_lds[(wr * 64 + bi * 16 + (lane & 15)) * 40 + (lane >> 4) * 8]);
    #pragma unroll
    for (int bj = 0; bj < 4; ++bj)
      bf[bj] = *reinterpret_cast<const short8*>(&b_lds[(wc * 64 + bj * 16 + (lane & 15)) * 40 + (lane >> 4) * 8]);
    #pragma unroll
    for (int bi = 0; bi < 4; ++bi) {
      #pragma unroll
      for (int bj = 0; bj < 4; ++bj)
        acc[bi][bj] = __builtin_amdgcn_mfma_f32_16x16x32_bf16(af[bi], bf[bj], acc[bi][bj], 0, 0, 0);
    }
    __syncthreads();
  }
  #pragma unroll
  for (int bi = 0; bi < 4; ++bi) {
    #pragma unroll
    for (int bj = 0; bj < 4; ++bj) {
      int col = n0 + wc * 64 + bj * 16 + (lane & 15);
      float bv = bias[col];
      #pragma unroll
      for (int r = 0; r < 4; ++r) {
        int row = m0 + wr * 64 + bi * 16 + (lane >> 4) * 4 + r;
        out[(size_t)row * NH + col] = acc[bi][bj][r] + bv;
      }
    }
  }
}

// ---- Phase 2: persistent recurrent scan (coherent sc1 state exchange, no cache fences) ----
__launch_bounds__(256)
__global__ void k_scan(const unsigned short* __restrict__ whT,
                       float* __restrict__ out,
                       unsigned short* __restrict__ sb0,
                       unsigned short* __restrict__ sb1,
                       unsigned int* __restrict__ cnt) {
  __shared__ unsigned short b_lds[32 * 2 * 64 * 8];  // 64KB Wh slice, fragment-packed
  __shared__ unsigned short r_lds[4 * 512];          // 4KB repack staging (1KB per wave)
  const int bx = blockIdx.x;
  const int bg = bx >> 5;   // batch group (64 rows)
  const int cg = bx & 31;   // column group (32 cols)
  const int tid = threadIdx.x, lane = tid & 63, w = tid >> 6;
  // stage WhT cols [cg*32, +32) fragment-packed
  {
    int c = tid >> 3;
    for (int it = 0; it < 32; ++it) {
      int kq = (tid & 7) + 8 * it;
      int k = kq * 4;
      uint2 v = *reinterpret_cast<const uint2*>(&whT[(size_t)(cg * 32 + c) * NH + k]);
      int kc = k >> 5, g = (k & 31) >> 3, i0 = k & 7, half = c >> 4;
      int ln = (c & 15) | (g << 4);
      *reinterpret_cast<uint2*>(&b_lds[((kc * 2 + half) * 64 + ln) * 8 + i0]) = v;
    }
  }
  __syncthreads();
  const int mg = bg * 4 + w;
  const int r0 = (lane >> 4) * 4;
  const int c0 = lane & 15;
  const size_t row_base = (size_t)(bg * 64 + w * 16 + r0);
  const int col_base = cg * 32 + c0;
  // prologue: xw for t=0
  float xwreg[2][4];
  #pragma unroll
  for (int bj = 0; bj < 2; ++bj)
    #pragma unroll
    for (int r = 0; r < 4; ++r)
      xwreg[bj][r] = out[(row_base + r) * NH + col_base + bj * 16];
  unsigned int target = 0;
  unsigned int* const myc = cnt + bg * 64;
  for (int t = 0; t < SEQ; ++t) {
    const uint32* cur = (const uint32*)((t & 1) ? sb1 : sb0);
    uint32* nxt = (uint32*)((t & 1) ? sb0 : sb1);
    // ---- A loads: 32 chunks x 4 lane-contiguous coherent dwords, batched up front ----
    uint32 av[32][4];
    const uint32* abase = cur + (size_t)mg * 32 * 256 + lane;
    #pragma unroll
    for (int kc = 0; kc < 32; ++kc) {
      #pragma unroll
      for (int j = 0; j < 4; ++j)
        av[kc][j] = __hip_atomic_load(abase + kc * 256 + j * 64,
                                      __ATOMIC_RELAXED, __HIP_MEMORY_SCOPE_AGENT);
    }
    f32x4 acc0 = {0.f, 0.f, 0.f, 0.f}, acc1 = {0.f, 0.f, 0.f, 0.f};
    #pragma unroll
    for (int kc = 0; kc < 32; ++kc) {
      uint4 u; u.x = av[kc][0]; u.y = av[kc][1]; u.z = av[kc][2]; u.w = av[kc][3];
      short8 a = __builtin_bit_cast(short8, u);
      short8 b0 = *reinterpret_cast<const short8*>(&b_lds[((kc * 2 + 0) * 64 + lane) * 8]);
      short8 b1 = *reinterpret_cast<const short8*>(&b_lds[((kc * 2 + 1) * 64 + lane) * 8]);
      acc0 = __builtin_amdgcn_mfma_f32_16x16x32_bf16(a, b0, acc0, 0, 0, 0);
      acc1 = __builtin_amdgcn_mfma_f32_16x16x32_bf16(a, b1, acc1, 0, 0, 0);
    }
    // ---- tanh, fp32 out store (plain), LDS repack ----
    #pragma unroll
    for (int bj = 0; bj < 2; ++bj) {
      const f32x4 accv = bj ? acc1 : acc0;
      #pragma unroll
      for (int r = 0; r < 4; ++r) {
        float v = tanhf(accv[r] + xwreg[bj][r]);
        out[((size_t)t * NB + row_base + r) * NH + col_base + bj * 16] = v;
        int kk = bj * 16 + c0;
        int g = kk >> 3, i = kk & 7, j = i >> 1, par = i & 1;
        int ln = (r0 + r) | (g << 4);
        r_lds[w * 512 + (j * 64 + ln) * 2 + par] = bf16b(v);
      }
    }
    __syncthreads();
    // ---- coherent state store: 4 lane-contiguous dwords per thread ----
    {
      const uint32* rl32 = (const uint32*)r_lds + w * 256;
      uint32* gdst = nxt + (size_t)(mg * 32 + cg) * 256 + lane;
      #pragma unroll
      for (int q = 0; q < 4; ++q)
        __hip_atomic_store(gdst + q * 64, rl32[q * 64 + lane],
                           __ATOMIC_RELAXED, __HIP_MEMORY_SCOPE_AGENT);
    }
    // stores must reach the coherent point before the arrival add
    asm volatile("s_waitcnt vmcnt(0)" ::: "memory");
    // ---- xw prefetch for t+1 (latency hidden under barrier wait) ----
    float nxw[2][4];
    #pragma unroll
    for (int bj = 0; bj < 2; ++bj)
      #pragma unroll
      for (int r = 0; r < 4; ++r)
        nxw[bj][r] = out[((size_t)(t + 1) * NB + row_base + r) * NH + col_base + bj * 16];
    // ---- group barrier: relaxed arrival + relaxed poll (no cache maintenance) ----
    target += 32;
    if (tid == 0) {
      __hip_atomic_fetch_add(myc, 1u, __ATOMIC_RELAXED, __HIP_MEMORY_SCOPE_AGENT);
      while (__hip_atomic_load(myc, __ATOMIC_RELAXED, __HIP_MEMORY_SCOPE_AGENT) < target) {}
    }
    __syncthreads();
    #pragma unroll
    for (int bj = 0; bj < 2; ++bj)
      #pragma unroll
      for (int r = 0; r < 4; ++r)
        xwreg[bj][r] = nxw[bj][r];
  }
}

extern "C" void kernel_launch(void* const* d_in, const int* in_sizes, int n_in,
                              void* d_out, int out_size, void* d_ws, size_t ws_size,
                              hipStream_t stream) {
  const float* x    = (const float*)d_in[0];
  const float* s0   = (const float*)d_in[1];
  const float* wx   = (const float*)d_in[2];
  const float* wh   = (const float*)d_in[3];
  const float* bias = (const float*)d_in[4];
  float* out = (float*)d_out;

  char* ws = (char*)d_ws;
  unsigned short* whT = (unsigned short*)(ws);                                  // 2 MB
  unsigned short* wxT = (unsigned short*)(ws + (2u << 20));                     // 1 MB
  unsigned short* sb0 = (unsigned short*)(ws + (3u << 20));                     // 256 KB
  unsigned short* sb1 = (unsigned short*)(ws + (3u << 20) + (256u << 10));      // 256 KB
  unsigned int*   cnt = (unsigned int*)(ws + (3u << 20) + (512u << 10));        // 512 B

  hipMemsetAsync(cnt, 0, 512, stream);
  k_cvt_whT<<<NH * NH / 256, 256, 0, stream>>>(wh, whT);
  k_cvt_wxT<<<NIN * NH / 256, 256, 0, stream>>>(wx, wxT);
  k_init_state<<<NB * NH / 256, 256, 0, stream>>>(s0, sb0);
  k_xw_gemm<<<(SEQ * NB / 128) * (NH / 128), 256, 0, stream>>>(x, wxT, bias, out);
  k_scan<<<64, 256, 0, stream>>>(whT, out, sb0, sb1, cnt);
  hipMemcpyAsync(out + (size_t)SEQ * NB * NH, out + (size_t)(SEQ - 1) * NB * NH,
                 (size_t)NB * NH * sizeof(float), hipMemcpyDeviceToDevice, stream);
}